// Round 9
// baseline (158.763 us; speedup 1.0000x reference)
//
#include <hip/hip_runtime.h>
#include <hip/hip_bf16.h>

#define NPIX 2304
#define C_IN 256
#define NHEADS 8
#define DHEAD 32

typedef float f32x4 __attribute__((ext_vector_type(4)));
typedef __bf16 bf16x8 __attribute__((ext_vector_type(8)));
typedef __bf16 bf16x4 __attribute__((ext_vector_type(4)));

#if __has_builtin(__builtin_amdgcn_exp2f)
#define EXP2F(x) __builtin_amdgcn_exp2f(x)
#else
#define EXP2F(x) exp2f(x)
#endif

__device__ inline void gload_lds16(const void* g, void* l) {
    __builtin_amdgcn_global_load_lds(
        (const __attribute__((address_space(1))) unsigned int*)g,
        (__attribute__((address_space(3))) unsigned int*)l, 16, 0, 0);
}

// ---------------------------------------------------------------------------
// prep_wx: merged weight-split + x-transpose.
//  blocks 0..575   : x fp32 [b][256c][2304n] -> xt bf16 [b][n][256c] (hi only)
//  blocks 576..1599: Wqkv/W0 rows -> [hi(256) | lo(256)] bf16
// ---------------------------------------------------------------------------
__global__ __launch_bounds__(256) void prep_wx(
    const float* __restrict__ Wq, const float* __restrict__ W0,
    const float* __restrict__ x,
    __bf16* __restrict__ wq, __bf16* __restrict__ w0,
    __bf16* __restrict__ xt)
{
    __shared__ unsigned int lds[64 * 69];
    const int id = blockIdx.x;
    const int t  = threadIdx.x;

    if (id >= 576) {                    // ---- weight split ----
        const int r = id - 576;         // 0..1023
        float v;
        __bf16* dst;
        if (r < 768) { v = Wq[r * 256 + t];         dst = wq + (size_t)r * 512; }
        else         { v = W0[(r - 768) * 256 + t]; dst = w0 + (size_t)(r - 768) * 512; }
        __bf16 hb = (__bf16)v;
        dst[t]       = hb;
        dst[256 + t] = (__bf16)(v - (float)hb);
        return;
    }

    // ---- x transpose ----
    const int n0 = (id % 36) * 64;
    const int c0 = ((id / 36) & 3) * 64;
    const int b  = id / 144;
    const float* xb = x + (size_t)b * C_IN * NPIX;

    #pragma unroll
    for (int p = 0; p < 4; ++p) {
        const int r    = (t >> 4) + p * 16;
        const int ncol = (t & 15) * 4;
        float4 v = *(const float4*)&xb[(size_t)(c0 + r) * NPIX + n0 + ncol];
        float a[4] = {v.x, v.y, v.z, v.w};
        #pragma unroll
        for (int i = 0; i < 4; ++i)
            lds[r * 69 + ncol + i] =
                (unsigned int)__builtin_bit_cast(unsigned short, (__bf16)a[i]);
    }
    __syncthreads();

    #pragma unroll
    for (int p = 0; p < 2; ++p) {
        const int nn = (t >> 3) + p * 32;
        const int ch = t & 7;
        bf16x8 h8;
        #pragma unroll
        for (int i = 0; i < 8; ++i)
            h8[i] = __builtin_bit_cast(__bf16,
                        (unsigned short)lds[(ch * 8 + i) * 69 + nn]);
        *(bf16x8*)&xt[((size_t)b * NPIX + n0 + nn) * 256 + c0 + ch * 8] = h8;
    }
}

// ---------------------------------------------------------------------------
// qkv_mfma: 64o x 128n GEMM tiles (B-reuse: acc += Whi.B + Wlo.B per chunk).
// Grid 864 = 8 XCD x 9 panels x 12 o-tiles (kq = mtt>>2 uniform/block).
// LDS per buf: A 128 rows(64 hi | 64 lo) x 64B = 8K + B 128 x 64B = 8K; x2.
// Epilogue: q -> qt bf16 [bh][n][32d]; khi/vg swizzled as before.
// ---------------------------------------------------------------------------
__global__ __launch_bounds__(256) void qkv_mfma(
    const __bf16* __restrict__ wq, const __bf16* __restrict__ xt,
    const float* __restrict__ bias, __bf16* __restrict__ qt,
    __bf16* __restrict__ khi, __bf16* __restrict__ vg)
{
    __shared__ alignas(16) unsigned char sm[32768];
    const int tid = threadIdx.x;
    const int l   = tid & 63;
    const int w   = tid >> 6;
    const int g   = l >> 4;
    const int c16 = l & 15;

    const int id  = blockIdx.x;
    const int xcd = id & 7;
    const int li  = id >> 3;            // 0..107
    const int pnl = xcd * 9 + li / 12;  // 0..71
    const int mtt = li % 12;            // o-tile of 64
    const int b   = pnl / 18;
    const int nt  = pnl - b * 18;
    const int n0  = nt * 128;
    const int kq  = mtt >> 2;
    const int seg = (mtt & 3) * 64;     // within-kq p offset

    const int wo = (w >> 1) * 32;
    const int wn = (w & 1) * 64;
    f32x4 acc[2][4] = {};

#define STG(buf, cs)                                                           \
    {                                                                          \
        unsigned char* lbs = sm + (buf) * 16384;                               \
        _Pragma("unroll")                                                      \
        for (int i = 0; i < 2; ++i) {                                          \
            const int row = i * 64 + (tid >> 2);                               \
            const int cl  = tid & 3;                                           \
            const int cg  = cl ^ (row & 3);                                    \
            const int pp  = seg + (row & 63);                                  \
            const int oA  = 24 * (pp >> 3) + 8 * kq + (pp & 7);                \
            gload_lds16(wq + (size_t)oA * 512 + i * 256 + (cs) * 32 + cg * 8,  \
                        lbs + row * 64 + cl * 16);                             \
        }                                                                      \
        _Pragma("unroll")                                                      \
        for (int i = 0; i < 2; ++i) {                                          \
            const int row = i * 64 + (tid >> 2);                               \
            const int cl  = tid & 3;                                           \
            const int cg  = cl ^ (row & 3);                                    \
            gload_lds16(xt + ((size_t)b * NPIX + n0 + row) * 256 +             \
                            (cs) * 32 + cg * 8,                                \
                        lbs + 8192 + row * 64 + cl * 16);                      \
        }                                                                      \
    }

    STG(0, 0);
    __syncthreads();
    #pragma unroll
    for (int cs = 0; cs < 8; ++cs) {
        const int buf = cs & 1;
        if (cs + 1 < 8) STG(buf ^ 1, cs + 1);
        unsigned char* lb = sm + buf * 16384;
        bf16x8 ah[2], al2[2], bf4[4];
        #pragma unroll
        for (int oi = 0; oi < 2; ++oi) {
            const int ra = wo + oi * 16 + c16;
            ah[oi]  = *(bf16x8*)(lb + ra * 64 + ((g ^ (ra & 3)) * 16));
            al2[oi] = *(bf16x8*)(lb + (64 + ra) * 64 + ((g ^ (ra & 3)) * 16));
        }
        #pragma unroll
        for (int ni = 0; ni < 4; ++ni) {
            const int rb = wn + ni * 16 + c16;
            bf4[ni] = *(bf16x8*)(lb + 8192 + rb * 64 + ((g ^ (rb & 3)) * 16));
        }
        #pragma unroll
        for (int oi = 0; oi < 2; ++oi)
            #pragma unroll
            for (int ni = 0; ni < 4; ++ni) {
                acc[oi][ni] = __builtin_amdgcn_mfma_f32_16x16x32_bf16(
                    ah[oi], bf4[ni], acc[oi][ni], 0, 0, 0);
                acc[oi][ni] = __builtin_amdgcn_mfma_f32_16x16x32_bf16(
                    al2[oi], bf4[ni], acc[oi][ni], 0, 0, 0);
            }
        __syncthreads();
    }
#undef STG

    const float qscale = 0.17677669529663687f * 1.4426950408889634f;
    #pragma unroll
    for (int oi = 0; oi < 2; ++oi) {
        #pragma unroll
        for (int rr = 0; rr < 4; ++rr) {
            const int pp = seg + wo + oi * 16 + 4 * g + rr;
            const int d  = pp >> 3;
            const int h  = pp & 7;
            const int o  = 24 * d + 8 * kq + h;
            const float bi = bias[o];
            const int bh_ = b * NHEADS + h;
            #pragma unroll
            for (int ni = 0; ni < 4; ++ni) {
                const int n = n0 + wn + ni * 16 + c16;
                const float val = acc[oi][ni][rr] + bi;
                if (kq == 0) {
                    qt[((size_t)bh_ * NPIX + n) * 32 + d] = (__bf16)(val * qscale);
                } else if (kq == 1) {
                    const int cp = ((d >> 3) + (n >> 1)) & 3;
                    khi[((size_t)bh_ * NPIX + n) * 32 + cp * 8 + (d & 7)] = (__bf16)val;
                } else {
                    const int cp = ((n >> 3) & 7) ^ (d & 7);
                    vg[((size_t)bh_ * DHEAD + d) * NPIX + (n >> 6) * 64 + cp * 8 + (n & 7)]
                        = (__bf16)val;
                }
            }
        }
    }
}

// ---------------------------------------------------------------------------
// attn_mfma: split-KV, no online softmax, plain-bf16 QK^T (1 MFMA per frag).
// q: qt bf16 [bh][n][32d] (pre-scaled by 32^-0.5*log2e).
// ---------------------------------------------------------------------------
__global__ __launch_bounds__(256) void attn_mfma(
    const __bf16* __restrict__ qt, const __bf16* __restrict__ khi,
    const __bf16* __restrict__ vg,
    float* __restrict__ po, float* __restrict__ lw)
{
    __shared__ alignas(16) unsigned char sm[32768];
    const int tid = threadIdx.x;
    const int l   = tid & 63;
    const int w   = tid >> 6;
    const int g   = l >> 4;
    const int c16 = l & 15;

    const int id = blockIdx.x;
    const int lg = (id & 7) * 144 + (id >> 3);
    const int bh = lg / 36;
    const int rem = lg - bh * 36;
    const int half = rem / 18;
    const int qt_i = rem - half * 18;

    const __bf16* qb  = qt  + (size_t)bh * NPIX * 32;
    const __bf16* khb = khi + (size_t)bh * NPIX * 32;
    const __bf16* vb  = vg  + (size_t)bh * DHEAD * NPIX;

    const int q0 = qt_i * 128 + w * 32;

    bf16x8 qh[2];
    #pragma unroll
    for (int qgi = 0; qgi < 2; ++qgi)
        qh[qgi] = *(const bf16x8*)&qb[(size_t)(q0 + qgi * 16 + c16) * 32 + g * 8];

    f32x4 o[2][2] = {};
    float lsum[2] = {0.f, 0.f};

    const int vd   = w * 8 + (l >> 3);
    const int kswz = (c16 >> 1) & 3;
    unsigned char* const wsl = sm + 16384 + w * 4096;

#define STAGE(buf, kb)                                                         \
    {                                                                          \
        const int j0s = (kb) * 64;                                             \
        unsigned char* lbs = sm + (buf) * 8192;                                \
        gload_lds16(khb + (size_t)(j0s + w * 16) * 32 + l * 8, lbs + w * 1024);\
        gload_lds16(vb + (size_t)vd * NPIX + j0s + (l & 7) * 8,                \
                    lbs + 4096 + w * 1024);                                    \
    }

    const int kb0 = half * 18;
    STAGE(0, kb0);
    __syncthreads();

    for (int t = 0; t < 18; ++t) {
        const int buf = t & 1;
        if (t + 1 < 18) STAGE(buf ^ 1, kb0 + t + 1);
        unsigned char* lb = sm + buf * 8192;

        f32x4 sv[2][4];
        __builtin_amdgcn_s_setprio(1);
        #pragma unroll
        for (int f = 0; f < 4; ++f) {
            const int ko = (c16 + 16 * f) * 64 + ((g + kswz) & 3) * 16;
            bf16x8 kh8 = *(bf16x8*)(lb + ko);
            #pragma unroll
            for (int qgi = 0; qgi < 2; ++qgi) {
                f32x4 acc = {0.f, 0.f, 0.f, 0.f};
                acc = __builtin_amdgcn_mfma_f32_16x16x32_bf16(kh8, qh[qgi], acc, 0, 0, 0);
                sv[qgi][f] = acc;
            }
        }
        __builtin_amdgcn_s_setprio(0);

        #pragma unroll
        for (int qgi = 0; qgi < 2; ++qgi) {
            float rs = 0.f;
            __bf16 pb[16];
            #pragma unroll
            for (int f = 0; f < 4; ++f)
                #pragma unroll
                for (int rr = 0; rr < 4; ++rr) {
                    const float p = EXP2F(sv[qgi][f][rr]);
                    rs += p;
                    pb[f * 4 + rr] = (__bf16)p;
                }
            lsum[qgi] += rs;
            const int qrow = qgi * 16 + c16;
            #pragma unroll
            for (int f = 0; f < 4; ++f) {
                const int ch = (2 * f + (g >> 1)) ^ (c16 & 7);
                *(bf16x4*)(wsl + qrow * 128 + ch * 16 + (g & 1) * 8) =
                    *(bf16x4*)&pb[f * 4];
            }
        }

        __builtin_amdgcn_s_setprio(1);
        #pragma unroll
        for (int kc = 0; kc < 2; ++kc) {
            const int vch = (((g + 4 * kc) ^ (c16 & 7))) * 16;
            bf16x8 va0 = *(bf16x8*)(lb + 4096 + c16 * 128 + vch);
            bf16x8 va1 = *(bf16x8*)(lb + 4096 + (16 + c16) * 128 + vch);
            #pragma unroll
            for (int qgi = 0; qgi < 2; ++qgi) {
                bf16x8 pf = *(bf16x8*)(wsl + (qgi * 16 + c16) * 128 + vch);
                o[qgi][0] = __builtin_amdgcn_mfma_f32_16x16x32_bf16(va0, pf, o[qgi][0], 0, 0, 0);
                o[qgi][1] = __builtin_amdgcn_mfma_f32_16x16x32_bf16(va1, pf, o[qgi][1], 0, 0, 0);
            }
        }
        __builtin_amdgcn_s_setprio(0);

        __syncthreads();
    }
#undef STAGE

    #pragma unroll
    for (int qgi = 0; qgi < 2; ++qgi) {
        lsum[qgi] += __shfl_xor(lsum[qgi], 16);
        lsum[qgi] += __shfl_xor(lsum[qgi], 32);
        const int n = q0 + qgi * 16 + c16;
        const size_t rbase = ((size_t)(half * 32 + bh) * NPIX + n) * 32;
        #pragma unroll
        for (int dh = 0; dh < 2; ++dh)
            *(f32x4*)&po[rbase + dh * 16 + 4 * g] = o[qgi][dh];
        if (g == 0)
            lw[(size_t)(half * 32 + bh) * NPIX + n] = lsum[qgi];
    }
}

// ---------------------------------------------------------------------------
// out_mfma: 64o x 128n GEMM with fused split-KV combine.
// Grid 288 = 8 XCD x 9 panels x 4 o-tiles.
// LDS per buf: A 8K + B 128x72B = 9216 -> 17408; x2 = 34816.
// ---------------------------------------------------------------------------
__global__ __launch_bounds__(256) void out_mfma(
    const __bf16* __restrict__ w0, const float* __restrict__ po,
    const float* __restrict__ lw, const float* __restrict__ bias,
    float* __restrict__ out)
{
    __shared__ alignas(16) unsigned char sm[34816];
    const int tid = threadIdx.x;
    const int l   = tid & 63;
    const int w   = tid >> 6;
    const int g   = l >> 4;
    const int c16 = l & 15;

    const int id  = blockIdx.x;
    const int xcd = id & 7;
    const int li  = id >> 3;            // 0..35
    const int pnl = xcd * 9 + (li >> 2);
    const int mt  = li & 3;
    const int b   = pnl / 18;
    const int nt  = pnl - b * 18;
    const int n0  = nt * 128;
    const int o0  = mt * 64;

    const int wo = (w >> 1) * 32;
    const int wn = (w & 1) * 64;
    f32x4 acc[2][4] = {};

    const int brow = tid >> 1;
    const int bch  = tid & 1;

#define STG_A(buf, cs)                                                         \
    {                                                                          \
        unsigned char* lbs = sm + (buf) * 17408;                               \
        _Pragma("unroll")                                                      \
        for (int i = 0; i < 2; ++i) {                                          \
            const int row = i * 64 + (tid >> 2);                               \
            const int cl  = tid & 3;                                           \
            const int cg  = cl ^ (row & 3);                                    \
            gload_lds16(w0 + (size_t)(o0 + (row & 63)) * 512 + i * 256 +       \
                            (cs) * 32 + cg * 8,                                \
                        lbs + row * 64 + cl * 16);                             \
        }                                                                      \
    }

    f32x4 r0[4], r1[4];
    float il;

#define LDB(cs)                                                                \
    {                                                                          \
        const int bh_ = b * 8 + (cs);                                          \
        const int n   = n0 + brow;                                             \
        const float l0 = lw[(size_t)bh_ * NPIX + n];                           \
        const float l1 = lw[(size_t)(32 + bh_) * NPIX + n];                    \
        il = 1.0f / (l0 + l1);                                                 \
        const float* s0 = &po[((size_t)bh_ * NPIX + n) * 32 + bch * 16];       \
        const float* s1 = &po[((size_t)(32 + bh_) * NPIX + n) * 32 + bch * 16];\
        _Pragma("unroll")                                                      \
        for (int k2 = 0; k2 < 4; ++k2) {                                       \
            r0[k2] = *(const f32x4*)(s0 + k2 * 4);                             \
            r1[k2] = *(const f32x4*)(s1 + k2 * 4);                             \
        }                                                                      \
    }

#define WRB(buf)                                                               \
    {                                                                          \
        unsigned char* lbs = sm + (buf) * 17408 + 8192;                        \
        _Pragma("unroll")                                                      \
        for (int k2 = 0; k2 < 2; ++k2) {                                       \
            bf16x8 v8;                                                         \
            _Pragma("unroll")                                                  \
            for (int e = 0; e < 4; ++e) {                                      \
                v8[e]     = (__bf16)((r0[2 * k2][e]     + r1[2 * k2][e])     * il); \
                v8[4 + e] = (__bf16)((r0[2 * k2 + 1][e] + r1[2 * k2 + 1][e]) * il); \
            }                                                                  \
            *(bf16x8*)(lbs + brow * 72 + bch * 32 + k2 * 16) = v8;             \
        }                                                                      \
    }

    STG_A(0, 0);
    LDB(0);
    WRB(0);
    __syncthreads();

    #pragma unroll
    for (int cs = 0; cs < 8; ++cs) {
        const int buf = cs & 1;
        if (cs + 1 < 8) {
            STG_A(buf ^ 1, cs + 1);
            LDB(cs + 1);
        }
        unsigned char* lb = sm + buf * 17408;
        bf16x8 ah[2], al2[2], bf4[4];
        #pragma unroll
        for (int oi = 0; oi < 2; ++oi) {
            const int ra = wo + oi * 16 + c16;
            ah[oi]  = *(bf16x8*)(lb + ra * 64 + ((g ^ (ra & 3)) * 16));
            al2[oi] = *(bf16x8*)(lb + (64 + ra) * 64 + ((g ^ (ra & 3)) * 16));
        }
        #pragma unroll
        for (int ni = 0; ni < 4; ++ni) {
            const int rb = wn + ni * 16 + c16;
            bf4[ni] = *(bf16x8*)(lb + 8192 + rb * 72 + g * 16);
        }
        #pragma unroll
        for (int oi = 0; oi < 2; ++oi)
            #pragma unroll
            for (int ni = 0; ni < 4; ++ni) {
                acc[oi][ni] = __builtin_amdgcn_mfma_f32_16x16x32_bf16(
                    ah[oi], bf4[ni], acc[oi][ni], 0, 0, 0);
                acc[oi][ni] = __builtin_amdgcn_mfma_f32_16x16x32_bf16(
                    al2[oi], bf4[ni], acc[oi][ni], 0, 0, 0);
            }
        if (cs + 1 < 8) WRB(buf ^ 1);
        __syncthreads();
    }
#undef STG_A
#undef LDB
#undef WRB

    #pragma unroll
    for (int oi = 0; oi < 2; ++oi) {
        #pragma unroll
        for (int rr = 0; rr < 4; ++rr) {
            const int o = o0 + wo + oi * 16 + 4 * g + rr;
            const float bi = bias[o];
            #pragma unroll
            for (int ni = 0; ni < 4; ++ni) {
                const int n = n0 + wn + ni * 16 + c16;
                out[((size_t)b * C_IN + o) * NPIX + n] = acc[oi][ni][rr] + bi;
            }
        }
    }
}

extern "C" void kernel_launch(void* const* d_in, const int* in_sizes, int n_in,
                              void* d_out, int out_size, void* d_ws, size_t ws_size,
                              hipStream_t stream) {
    const float* x    = (const float*)d_in[0];
    const float* Wqkv = (const float*)d_in[1];
    const float* bqkv = (const float*)d_in[2];
    const float* W0   = (const float*)d_in[3];
    const float* b0   = (const float*)d_in[4];
    float* out = (float*)d_out;

    char* ws = (char*)d_ws;
    __bf16* wq  = (__bf16*)(ws);                    //   786,432
    __bf16* w0  = (__bf16*)(ws + 786432);           //   262,144
    __bf16* xt  = (__bf16*)(ws + 1048576);          // 4,718,592
    __bf16* qt  = (__bf16*)(ws + 5767168);          // 4,718,592
    __bf16* khi = (__bf16*)(ws + 10485760);         // 4,718,592
    __bf16* vg  = (__bf16*)(ws + 15204352);         // 4,718,592
    float*  po  = (float*) (ws + 19922944);         // 18,874,368
    float*  lw  = (float*) (ws + 38797312);         //   589,824 -> 39.4 MB

    prep_wx<<<dim3(1600), 256, 0, stream>>>(Wqkv, W0, x, wq, w0, xt);
    qkv_mfma<<<dim3(864), 256, 0, stream>>>(wq, xt, bqkv, qt, khi, vg);
    attn_mfma<<<dim3(1152), 256, 0, stream>>>(qt, khi, vg, po, lw);
    out_mfma<<<dim3(288), 256, 0, stream>>>(w0, po, lw, b0, out);
}